// Round 8
// baseline (33.179 us; speedup 1.0000x reference)
//
#include <hip/hip_runtime.h>
#include <math.h>

// Problem constants: B=16, N=M=4096, K=64.
#define BB 16
#define NN 4096
#define MM 4096
#define NSLICE 2
#define SLICE_COLS 2048               // cols staged per block
#define NJT (SLICE_COLS / 64)         // 32
#define ROWS_PER_WAVE 64              // 2 x 32-row A-frags
#define ROWS_PER_BLOCK 256            // 4 waves
#define NROWS_TOTAL (2 * BB * NN)     // 131072
#define NCHAMFER 1024                 // 16 tiles * 2 slices * 16 b * 2 dir
#define EPW 2176                      // epilogue floats per wave (32*68)

typedef __attribute__((ext_vector_type(8))) short bf16x8;
typedef __attribute__((ext_vector_type(16))) float f32x16;

static __device__ inline unsigned short f2bf(float f) {
    unsigned int u = __float_as_uint(f);
    return (unsigned short)((u + 0x7FFFu + ((u >> 16) & 1u)) >> 16);  // RNE
}
static __device__ inline bf16x8 bzero() {
    bf16x8 z;
    #pragma unroll
    for (int i = 0; i < 8; ++i) z[i] = 0;
    return z;
}
static __device__ inline f32x16 fzero16() {
    f32x16 z;
    #pragma unroll
    for (int i = 0; i < 16; ++i) z[i] = 0.f;
    return z;
}

#define MFMA32(Af, Bf, Cf) __builtin_amdgcn_mfma_f32_32x32x16_bf16(Af, Bf, Cf, 0, 0, 0)

// ---------------------------------------------------------------------------
// Pass A (+reg). d2 complete in-MFMA: d2 = dot_K5([-2p,p2,1],[t,1,t2]).
// OCCUPANCY-FIRST config: 4 blocks/CU (16 waves/CU, 4 waves/SIMD) so MFMA
// latency + min3 VALU overlap ACROSS waves. 2 A-frags/wave (64 rows), 4
// waves = 256 rows/block, 2048-col M-slice in LDS (32KB); VGPR <= 128 via
// __launch_bounds__(256,4). Per-slice row-min plain-stored to ws.
// Blocks [1024,1040): regularizer via MFMA (one wave).
// ---------------------------------------------------------------------------
__global__ __launch_bounds__(256, 4) void chamfer_min_kernel(
    const float* __restrict__ pred, const float* __restrict__ gt,
    const float* __restrict__ trans, float* __restrict__ wsmin,
    float* __restrict__ out)
{
    const int bx  = blockIdx.x;
    const int tid = threadIdx.x;

    if (bx >= NCHAMFER) {
        // ------------------------- regularizer -------------------------
        if (tid < 64) {
            const int b = bx - NCHAMFER;
            const int lane = tid;
            const int hi = lane >> 5, li = lane & 31;
            const float* T = trans + (size_t)b * 64 * 64;
            float fsum = 0.f;
            #pragma unroll
            for (int fi = 0; fi < 2; ++fi) {
                bf16x8 fa[4];
                #pragma unroll
                for (int s = 0; s < 4; ++s) {
                    const float* rp = T + (size_t)(fi * 32 + li) * 64 + s * 16 + hi * 8;
                    const float4 u0 = *(const float4*)rp;
                    const float4 u1 = *(const float4*)(rp + 4);
                    bf16x8 fr;
                    fr[0] = (short)f2bf(u0.x); fr[1] = (short)f2bf(u0.y);
                    fr[2] = (short)f2bf(u0.z); fr[3] = (short)f2bf(u0.w);
                    fr[4] = (short)f2bf(u1.x); fr[5] = (short)f2bf(u1.y);
                    fr[6] = (short)f2bf(u1.z); fr[7] = (short)f2bf(u1.w);
                    fa[s] = fr;
                }
                #pragma unroll
                for (int fj = 0; fj < 2; ++fj) {
                    f32x16 a = fzero16();
                    #pragma unroll
                    for (int s = 0; s < 4; ++s) {
                        const float* rp = T + (size_t)(fj * 32 + li) * 64 + s * 16 + hi * 8;
                        const float4 u0 = *(const float4*)rp;
                        const float4 u1 = *(const float4*)(rp + 4);
                        bf16x8 fr;
                        fr[0] = (short)f2bf(u0.x); fr[1] = (short)f2bf(u0.y);
                        fr[2] = (short)f2bf(u0.z); fr[3] = (short)f2bf(u0.w);
                        fr[4] = (short)f2bf(u1.x); fr[5] = (short)f2bf(u1.y);
                        fr[6] = (short)f2bf(u1.z); fr[7] = (short)f2bf(u1.w);
                        a = MFMA32(fa[s], fr, a);
                    }
                    #pragma unroll
                    for (int r = 0; r < 16; ++r) {
                        const int row = fi * 32 + (r & 3) + 8 * (r >> 2) + 4 * hi;
                        const int col = fj * 32 + li;
                        const float d = a[r] - ((row == col) ? 1.0f : 0.0f);
                        fsum = fmaf(d, d, fsum);
                    }
                }
            }
            #pragma unroll
            for (int off = 32; off > 0; off >>= 1)
                fsum += __shfl_down(fsum, off, 64);
            if (lane == 0)
                atomicAdd(out, (0.1f / (float)BB) * sqrtf(fsum));
        }
        return;
    }

    // --------------------------- chamfer -----------------------------
    __shared__ __align__(16) float smem[4 * EPW];   // 34.8KB: stage 32KB | epi

    const int lane = tid & 63;
    const int w    = tid >> 6;
    const int li   = lane & 31;
    const int hi   = lane >> 5;
    // bx = tile + 16*(mslice + 2*(b + 16*dir))
    const int tile   = bx & 15;
    const int mslice = (bx >> 4) & 1;
    const int b      = (bx >> 5) & 15;
    const int dir    = bx >> 9;
    const float* rows = dir ? gt : pred;
    const float* cols = dir ? pred : gt;
    const float* rb = rows + (size_t)b * NN * 3;
    const float* cb = cols + ((size_t)b * MM + (size_t)mslice * SLICE_COLS) * 3;

    // A-frags: lanes 0-31 carry k=0..7 (k0..4 used); lanes 32-63 zero.
    const int rbase = tile * ROWS_PER_BLOCK + w * ROWS_PER_WAVE;
    bf16x8 A0 = bzero(), A1 = bzero();
    if (lane < 32) {
        #pragma unroll
        for (int f = 0; f < 2; ++f) {
            const float* rp = rb + (size_t)(rbase + f * 32 + li) * 3;
            const float px = rp[0], py = rp[1], pz = rp[2];
            const float p2 = px * px + py * py + pz * pz;
            bf16x8 fr = bzero();
            fr[0] = (short)f2bf(-2.f * px);
            fr[1] = (short)f2bf(-2.f * py);
            fr[2] = (short)f2bf(-2.f * pz);
            fr[3] = (short)f2bf(p2);
            fr[4] = (short)0x3F80;          // 1.0
            if (f == 0) A0 = fr; else A1 = fr;
        }
    }

    // Stage slice (float2-vectorized): packed bf16x8 per col = (t,1,t2,0,0,0).
    uint4* sB = (uint4*)smem;
    #pragma unroll
    for (int i = 0; i < SLICE_COLS / 512; ++i) {
        const int c0 = i * 512 + 2 * tid;            // col pair
        const float2* sp = (const float2*)(cb + (size_t)c0 * 3);
        const float2 v0 = sp[0], v1 = sp[1], v2 = sp[2];
        const float t2a = v0.x * v0.x + v0.y * v0.y + v1.x * v1.x;
        const float t2b = v1.y * v1.y + v2.x * v2.x + v2.y * v2.y;
        uint4 pa, pb;
        pa.x = (unsigned)f2bf(v0.x) | ((unsigned)f2bf(v0.y) << 16);
        pa.y = (unsigned)f2bf(v1.x) | (0x3F80u << 16);
        pa.z = (unsigned)f2bf(t2a);
        pa.w = 0u;
        pb.x = (unsigned)f2bf(v1.y) | ((unsigned)f2bf(v2.x) << 16);
        pb.y = (unsigned)f2bf(v2.y) | (0x3F80u << 16);
        pb.z = (unsigned)f2bf(t2b);
        pb.w = 0u;
        sB[c0]     = pa;
        sB[c0 + 1] = pb;
    }
    __syncthreads();

    float mv0[16], mv1[16];
    #pragma unroll
    for (int r = 0; r < 16; ++r) { mv0[r] = 3.4e38f; mv1[r] = 3.4e38f; }

    const f32x16 Z = fzero16();
    const bf16x8* sBf = (const bf16x8*)smem;

    for (int jt = 0; jt < NJT; ++jt) {
        const bf16x8 c1 = sBf[jt * 64 + li];         // lanes>=32 dup (A=0 there)
        const bf16x8 c2 = sBf[jt * 64 + 32 + li];
        f32x16 a0 = MFMA32(A0, c1, Z);
        f32x16 a1 = MFMA32(A0, c2, Z);
        f32x16 a2 = MFMA32(A1, c1, Z);
        f32x16 a3 = MFMA32(A1, c2, Z);
        #pragma unroll
        for (int r = 0; r < 16; ++r)
            mv0[r] = fminf(fminf(a0[r], a1[r]), mv0[r]);   // v_min3_f32
        #pragma unroll
        for (int r = 0; r < 16; ++r)
            mv1[r] = fminf(fminf(a2[r], a3[r]), mv1[r]);
    }

    // Epilogue: transpose partial mins via LDS [li][row 0..63], stride 68.
    // acc mapping: row_local = f*32 + (r&3) + 8*(r>>2) + 4*hi, col = li.
    __syncthreads();
    {
        float* wb = smem + w * EPW + li * 68;
        #pragma unroll
        for (int q = 0; q < 4; ++q) {
            const int rl = q * 8 + hi * 4;
            *(float4*)&wb[rl]      = make_float4(mv0[4*q], mv0[4*q+1], mv0[4*q+2], mv0[4*q+3]);
            *(float4*)&wb[rl + 32] = make_float4(mv1[4*q], mv1[4*q+1], mv1[4*q+2], mv1[4*q+3]);
        }
    }
    __syncthreads();

    // 256 rows, 256 threads: thread reads its row across 32 col-partials.
    const int wsrc = tid >> 6, rl = tid & 63;
    const float* rb2 = smem + wsrc * EPW + rl;
    float m = 3.4e38f;
    #pragma unroll
    for (int c = 0; c < 32; ++c) m = fminf(m, rb2[c * 68]);
    wsmin[(size_t)mslice * NROWS_TOTAL + (size_t)(dir * BB + b) * NN
          + tile * ROWS_PER_BLOCK + tid] = m;
}

// ---------------------------------------------------------------------------
// Pass B: min over the 2 slices, sqrt, mean-reduce, atomicAdd to out.
// ---------------------------------------------------------------------------
__global__ __launch_bounds__(256) void chamfer_finish_kernel(
    const float* __restrict__ wsmin, float* __restrict__ out)
{
    const int tid = threadIdx.x;
    const int g = blockIdx.x * 256 + tid;           // 0 .. 131071
    const float v = fminf(wsmin[g], wsmin[NROWS_TOTAL + g]);
    float d = sqrtf(fmaxf(v, 0.0f));
    #pragma unroll
    for (int off = 32; off > 0; off >>= 1)
        d += __shfl_down(d, off, 64);
    __shared__ float ssum[4];
    if ((tid & 63) == 0) ssum[tid >> 6] = d;
    __syncthreads();
    if (tid == 0) {
        const float s = ssum[0] + ssum[1] + ssum[2] + ssum[3];
        atomicAdd(out, s * (1.0f / ((float)BB * (float)NN)));
    }
}

extern "C" void kernel_launch(void* const* d_in, const int* in_sizes, int n_in,
                              void* d_out, int out_size, void* d_ws, size_t ws_size,
                              hipStream_t stream)
{
    const float* pred  = (const float*)d_in[0];
    const float* gt    = (const float*)d_in[1];
    const float* trans = (const float*)d_in[2];
    float* out = (float*)d_out;
    float* wsmin = (float*)d_ws;   // 2 * 131072 floats = 1 MB, plain stores

    hipMemsetAsync(out, 0, sizeof(float), stream);
    chamfer_min_kernel<<<dim3(NCHAMFER + BB), dim3(256), 0, stream>>>(
        pred, gt, trans, wsmin, out);
    chamfer_finish_kernel<<<dim3(NROWS_TOTAL / 256), dim3(256), 0, stream>>>(
        wsmin, out);
}

// Round 9
// 33.161 us; speedup vs baseline: 1.0005x; 1.0005x over previous
//
#include <hip/hip_runtime.h>
#include <math.h>

// Problem constants: B=16, N=M=4096, K=64.
#define BB 16
#define NN 4096
#define MM 4096
#define NSLICE 2
#define SLICE_COLS 2048               // cols staged per block
#define NJT (SLICE_COLS / 64)         // 32
#define ROWS_PER_BLOCK 256            // 4 waves x 64 rows
#define NCHAMFER 512                  // 16 row-tiles * 2 col-slices * 16 b
#define EPW 2176                      // row-epilogue floats per wave (32*68)
// workspace layout (floats): ws_row[BB*NSLICE*NN] then ws_col[BB*16*NSLICE*2048]
#define WSCOL_OFF (BB * NSLICE * NN)  // 131072

typedef __attribute__((ext_vector_type(8))) short bf16x8;
typedef __attribute__((ext_vector_type(16))) float f32x16;

static __device__ inline unsigned short f2bf(float f) {
    unsigned int u = __float_as_uint(f);
    return (unsigned short)((u + 0x7FFFu + ((u >> 16) & 1u)) >> 16);  // RNE
}
static __device__ inline bf16x8 bzero() {
    bf16x8 z;
    #pragma unroll
    for (int i = 0; i < 8; ++i) z[i] = 0;
    return z;
}
static __device__ inline f32x16 fzero16() {
    f32x16 z;
    #pragma unroll
    for (int i = 0; i < 16; ++i) z[i] = 0.f;
    return z;
}

#define MFMA32(Af, Bf, Cf) __builtin_amdgcn_mfma_f32_32x32x16_bf16(Af, Bf, Cf, 0, 0, 0)

// ---------------------------------------------------------------------------
// ONE distance matrix, BOTH reductions. d2 = dot_K5([-2p,p2,1],[t,1,t2]) in
// a single 32x32x16 MFMA. Rows (pred) reduce in registers (row-min, as R8).
// Cols (gt) reduce via ds_atomic_min_u32 into a block-wide colmin[2048]
// (d2+1.0 > 0 => float bits monotone under unsigned min). Halves MFMA count,
// ds_read traffic and staging vs R8 (no dir dimension).
// Grid: 512 chamfer blocks (16 tiles * 2 slices * 16 b) + 16 reg blocks.
// ---------------------------------------------------------------------------
__global__ __launch_bounds__(256, 2) void chamfer_min_kernel(
    const float* __restrict__ pred, const float* __restrict__ gt,
    const float* __restrict__ trans, float* __restrict__ ws,
    float* __restrict__ out)
{
    const int bx  = blockIdx.x;
    const int tid = threadIdx.x;

    if (bx >= NCHAMFER) {
        // ------------------------- regularizer -------------------------
        if (tid < 64) {
            const int b = bx - NCHAMFER;
            const int lane = tid;
            const int hi = lane >> 5, li = lane & 31;
            const float* T = trans + (size_t)b * 64 * 64;
            bf16x8 frag[2][4];
            #pragma unroll
            for (int h = 0; h < 2; ++h)
                #pragma unroll
                for (int s = 0; s < 4; ++s) {
                    const float* rp = T + (size_t)(h * 32 + li) * 64 + s * 16 + hi * 8;
                    const float4 u0 = *(const float4*)rp;
                    const float4 u1 = *(const float4*)(rp + 4);
                    bf16x8 fr;
                    fr[0] = (short)f2bf(u0.x); fr[1] = (short)f2bf(u0.y);
                    fr[2] = (short)f2bf(u0.z); fr[3] = (short)f2bf(u0.w);
                    fr[4] = (short)f2bf(u1.x); fr[5] = (short)f2bf(u1.y);
                    fr[6] = (short)f2bf(u1.z); fr[7] = (short)f2bf(u1.w);
                    frag[h][s] = fr;
                }
            float fsum = 0.f;
            #pragma unroll
            for (int fi = 0; fi < 2; ++fi)
                #pragma unroll
                for (int fj = 0; fj < 2; ++fj) {
                    f32x16 a = fzero16();
                    #pragma unroll
                    for (int s = 0; s < 4; ++s)
                        a = MFMA32(frag[fi][s], frag[fj][s], a);
                    #pragma unroll
                    for (int r = 0; r < 16; ++r) {
                        const int row = fi * 32 + (r & 3) + 8 * (r >> 2) + 4 * hi;
                        const int col = fj * 32 + li;
                        const float d = a[r] - ((row == col) ? 1.0f : 0.0f);
                        fsum = fmaf(d, d, fsum);
                    }
                }
            #pragma unroll
            for (int off = 32; off > 0; off >>= 1)
                fsum += __shfl_down(fsum, off, 64);
            if (lane == 0)
                atomicAdd(out, (0.1f / (float)BB) * sqrtf(fsum));
        }
        return;
    }

    // --------------------------- chamfer -----------------------------
    __shared__ __align__(16) float smem[8704];       // stage 32KB | row-epi 34.8KB
    __shared__ unsigned int colmin[SLICE_COLS];      // 8KB block-wide col mins

    const int lane = tid & 63;
    const int w    = tid >> 6;
    const int li   = lane & 31;
    const int hi   = lane >> 5;
    const int tile   = bx & 15;                      // row tile 0..15
    const int mslice = (bx >> 4) & 1;                // col slice 0..1
    const int b      = bx >> 5;                      // batch 0..15
    const float* rb = pred + (size_t)b * NN * 3;
    const float* cb = gt + ((size_t)b * MM + (size_t)mslice * SLICE_COLS) * 3;

    // A-frags (pred rows): lanes 0-31 carry k=0..7 (k0..4 used); lanes 32-63 zero.
    const int rbase = tile * ROWS_PER_BLOCK + w * 64;
    bf16x8 A0 = bzero(), A1 = bzero();
    if (lane < 32) {
        #pragma unroll
        for (int f = 0; f < 2; ++f) {
            const float* rp = rb + (size_t)(rbase + f * 32 + li) * 3;
            const float px = rp[0], py = rp[1], pz = rp[2];
            const float p2 = px * px + py * py + pz * pz;
            bf16x8 fr = bzero();
            fr[0] = (short)f2bf(-2.f * px);
            fr[1] = (short)f2bf(-2.f * py);
            fr[2] = (short)f2bf(-2.f * pz);
            fr[3] = (short)f2bf(p2);
            fr[4] = (short)0x3F80;          // 1.0
            if (f == 0) A0 = fr; else A1 = fr;
        }
    }

    // Stage gt slice: packed bf16x8 per col = (t,1,t2,0,0,0); init colmin.
    uint4* sB = (uint4*)smem;
    #pragma unroll
    for (int i = 0; i < SLICE_COLS / 512; ++i) {
        const int c0 = i * 512 + 2 * tid;            // col pair
        const float2* sp = (const float2*)(cb + (size_t)c0 * 3);
        const float2 v0 = sp[0], v1 = sp[1], v2 = sp[2];
        const float t2a = v0.x * v0.x + v0.y * v0.y + v1.x * v1.x;
        const float t2b = v1.y * v1.y + v2.x * v2.x + v2.y * v2.y;
        uint4 pa, pb;
        pa.x = (unsigned)f2bf(v0.x) | ((unsigned)f2bf(v0.y) << 16);
        pa.y = (unsigned)f2bf(v1.x) | (0x3F80u << 16);
        pa.z = (unsigned)f2bf(t2a);
        pa.w = 0u;
        pb.x = (unsigned)f2bf(v1.y) | ((unsigned)f2bf(v2.x) << 16);
        pb.y = (unsigned)f2bf(v2.y) | (0x3F80u << 16);
        pb.z = (unsigned)f2bf(t2b);
        pb.w = 0u;
        sB[c0]     = pa;
        sB[c0 + 1] = pb;
    }
    #pragma unroll
    for (int i = 0; i < SLICE_COLS / 256; ++i)
        colmin[i * 256 + tid] = 0x7F7FFFFFu;         // FLT_MAX bits
    __syncthreads();

    float mv0[16], mv1[16];
    #pragma unroll
    for (int r = 0; r < 16; ++r) { mv0[r] = 3.4e38f; mv1[r] = 3.4e38f; }

    const f32x16 Z = fzero16();
    const bf16x8* sBf = (const bf16x8*)smem;

    #pragma unroll 2
    for (int jt = 0; jt < NJT; ++jt) {
        const bf16x8 c1 = sBf[jt * 64 + li];         // lanes>=32 dup (A=0 there)
        const bf16x8 c2 = sBf[jt * 64 + 32 + li];
        f32x16 a0 = MFMA32(A0, c1, Z);
        f32x16 a1 = MFMA32(A0, c2, Z);
        f32x16 a2 = MFMA32(A1, c1, Z);
        f32x16 a3 = MFMA32(A1, c2, Z);
        // row mins (pred side)
        #pragma unroll
        for (int r = 0; r < 16; ++r)
            mv0[r] = fminf(fminf(a0[r], a1[r]), mv0[r]);   // v_min3_f32
        #pragma unroll
        for (int r = 0; r < 16; ++r)
            mv1[r] = fminf(fminf(a2[r], a3[r]), mv1[r]);
        // col mins (gt side): this lane's 32 rows for col jt*64+li (a0,a2)
        // and col jt*64+32+li (a1,a3); +1.0 bias keeps bits monotone.
        float tA = fminf(a0[0], a0[1]);
        #pragma unroll
        for (int i = 1; i < 8; ++i) tA = fminf(fminf(a0[2*i], a0[2*i+1]), tA);
        #pragma unroll
        for (int i = 0; i < 8; ++i) tA = fminf(fminf(a2[2*i], a2[2*i+1]), tA);
        float tB = fminf(a1[0], a1[1]);
        #pragma unroll
        for (int i = 1; i < 8; ++i) tB = fminf(fminf(a1[2*i], a1[2*i+1]), tB);
        #pragma unroll
        for (int i = 0; i < 8; ++i) tB = fminf(fminf(a3[2*i], a3[2*i+1]), tB);
        atomicMin(&colmin[jt * 64 + li],      __float_as_uint(tA + 1.0f));
        atomicMin(&colmin[jt * 64 + 32 + li], __float_as_uint(tB + 1.0f));
    }

    // Row epilogue: transpose partial mins via LDS [li][row 0..63], stride 68.
    // acc mapping: row_local = f*32 + (r&3) + 8*(r>>2) + 4*hi, col-part = li.
    __syncthreads();                                  // colmin final, stage free
    {
        float* wb = smem + w * EPW + li * 68;
        #pragma unroll
        for (int q = 0; q < 4; ++q) {
            const int rl = q * 8 + hi * 4;
            *(float4*)&wb[rl]      = make_float4(mv0[4*q], mv0[4*q+1], mv0[4*q+2], mv0[4*q+3]);
            *(float4*)&wb[rl + 32] = make_float4(mv1[4*q], mv1[4*q+1], mv1[4*q+2], mv1[4*q+3]);
        }
    }
    __syncthreads();

    // rows: 256 rows, 256 threads; plain store (unique writer per (b,slice,row))
    {
        const int wsrc = tid >> 6, rl = tid & 63;
        const float* rb2 = smem + wsrc * EPW + rl;
        float m = 3.4e38f;
        #pragma unroll
        for (int c = 0; c < 32; ++c) m = fminf(m, rb2[c * 68]);
        ws[((size_t)b * NSLICE + mslice) * NN + tile * ROWS_PER_BLOCK + tid] = m;
    }
    // cols: 2048 cols, 8 per thread; decode bias; unique writer per (b,tile,slice,col)
    {
        float* wc = ws + WSCOL_OFF
                  + (((size_t)b * 16 + tile) * NSLICE + mslice) * SLICE_COLS;
        #pragma unroll
        for (int i = 0; i < SLICE_COLS / 256; ++i) {
            const int c = i * 256 + tid;
            wc[c] = __uint_as_float(colmin[c]) - 1.0f;
        }
    }
}

// ---------------------------------------------------------------------------
// Finish: rows min over 2 slices; cols min over 16 row-tiles; sqrt; mean.
// ---------------------------------------------------------------------------
__global__ __launch_bounds__(256) void chamfer_finish_kernel(
    const float* __restrict__ ws, float* __restrict__ out)
{
    const int tid = threadIdx.x;
    const int g = blockIdx.x * 256 + tid;           // 0 .. 131071
    float v;
    if (g < BB * NN) {                              // pred rows
        const int b = g >> 12, n = g & (NN - 1);
        const float* p = ws + ((size_t)b * NSLICE) * NN + n;
        v = fminf(p[0], p[NN]);
    } else {                                        // gt cols
        const int h = g - BB * NN;
        const int b = h >> 12, m = h & (MM - 1);
        const int s = m >> 11, c = m & (SLICE_COLS - 1);
        const float* p = ws + WSCOL_OFF + (((size_t)b * 16) * NSLICE + s) * SLICE_COLS + c;
        v = p[0];
        #pragma unroll
        for (int t = 1; t < 16; ++t)
            v = fminf(v, p[(size_t)t * NSLICE * SLICE_COLS]);
    }
    float d = sqrtf(fmaxf(v, 0.0f));
    #pragma unroll
    for (int off = 32; off > 0; off >>= 1)
        d += __shfl_down(d, off, 64);
    __shared__ float ssum[4];
    if ((tid & 63) == 0) ssum[tid >> 6] = d;
    __syncthreads();
    if (tid == 0) {
        const float s = ssum[0] + ssum[1] + ssum[2] + ssum[3];
        atomicAdd(out, s * (1.0f / ((float)BB * (float)NN)));
    }
}

extern "C" void kernel_launch(void* const* d_in, const int* in_sizes, int n_in,
                              void* d_out, int out_size, void* d_ws, size_t ws_size,
                              hipStream_t stream)
{
    const float* pred  = (const float*)d_in[0];
    const float* gt    = (const float*)d_in[1];
    const float* trans = (const float*)d_in[2];
    float* out = (float*)d_out;
    float* ws = (float*)d_ws;   // 131072 + 1048576 floats, plain stores

    hipMemsetAsync(out, 0, sizeof(float), stream);
    chamfer_min_kernel<<<dim3(NCHAMFER + BB), dim3(256), 0, stream>>>(
        pred, gt, trans, ws, out);
    chamfer_finish_kernel<<<dim3((2 * BB * NN) / 256), dim3(256), 0, stream>>>(
        ws, out);
}